// Round 1
// baseline (1478.572 us; speedup 1.0000x reference)
//
#include <hip/hip_runtime.h>
#include <hip/hip_bf16.h>

#define N_NODES 10000
#define N_EDGES 160000
#define N_GRAPHS 64
#define EPS 1e-5f

// ---------------- CSR build ----------------
__global__ void hist_kernel(const int* __restrict__ dst, int* __restrict__ counts, int E) {
    int e = blockIdx.x * blockDim.x + threadIdx.x;
    if (e < E) atomicAdd(&counts[dst[e]], 1);
}

__global__ void scan_kernel(const int* __restrict__ counts, int* __restrict__ offs,
                            int* __restrict__ pos, int n) {
    __shared__ int ls[1024];
    int t = threadIdx.x;
    int per = (n + 1023) / 1024;
    int st = t * per, en = min(st + per, n);
    int s = 0;
    for (int i = st; i < en; i++) s += counts[i];
    ls[t] = s;
    __syncthreads();
    for (int off = 1; off < 1024; off <<= 1) {
        int v = 0;
        if (t >= off) v = ls[t - off];
        __syncthreads();
        if (t >= off) ls[t] += v;
        __syncthreads();
    }
    int excl = (t == 0) ? 0 : ls[t - 1];
    for (int i = st; i < en; i++) {
        offs[i] = excl;
        pos[i] = excl;
        excl += counts[i];
    }
    if (t == 1023) offs[n] = ls[1023];
}

__global__ void scatter_kernel(const int* __restrict__ src, const int* __restrict__ dst,
                               int* __restrict__ pos, int* __restrict__ csr_src, int E) {
    int e = blockIdx.x * blockDim.x + threadIdx.x;
    if (e < E) {
        int p = atomicAdd(&pos[dst[e]], 1);
        csr_src[p] = src[e];
    }
}

// ---------------- fused 4-matrix GEMM (fp32) ----------------
// C = A @ W ; A: N x K row-major, W: K x M row-major, C: N x M row-major
// blockIdx.z in {0..3} selects (W, C) pair.
#define BM 64
#define BN 64
#define BK 16
__global__ void gemm4_kernel(const float* __restrict__ A,
                             const float* __restrict__ W0, const float* __restrict__ W1,
                             const float* __restrict__ W2, const float* __restrict__ W3,
                             float* __restrict__ C0, float* __restrict__ C1,
                             float* __restrict__ C2, float* __restrict__ C3,
                             int N, int K, int M) {
    const float* B;
    float* C;
    switch (blockIdx.z) {
        case 0: B = W0; C = C0; break;
        case 1: B = W1; C = C1; break;
        case 2: B = W2; C = C2; break;
        default: B = W3; C = C3; break;
    }
    __shared__ float As[BK][BM + 1];
    __shared__ float Bs[BK][BN + 1];
    int tid = threadIdx.x;          // 256 threads
    int tx = tid & 15, ty = tid >> 4;
    int row0 = blockIdx.y * BM, col0 = blockIdx.x * BN;
    float acc[4][4] = {};
    for (int kt = 0; kt < K; kt += BK) {
        for (int i = tid; i < BM * BK; i += 256) {
            int m = i >> 4, kk = i & 15;
            float val = (row0 + m < N) ? A[(size_t)(row0 + m) * K + kt + kk] : 0.f;
            As[kk][m] = val;
        }
        for (int i = tid; i < BK * BN; i += 256) {
            int kk = i >> 6, n = i & 63;
            Bs[kk][n] = B[(size_t)(kt + kk) * M + col0 + n];
        }
        __syncthreads();
        for (int kk = 0; kk < BK; kk++) {
            float a[4], b[4];
#pragma unroll
            for (int i = 0; i < 4; i++) a[i] = As[kk][ty * 4 + i];
#pragma unroll
            for (int j = 0; j < 4; j++) b[j] = Bs[kk][tx * 4 + j];
#pragma unroll
            for (int i = 0; i < 4; i++)
#pragma unroll
                for (int j = 0; j < 4; j++) acc[i][j] += a[i] * b[j];
        }
        __syncthreads();
    }
    for (int i = 0; i < 4; i++) {
        int m = row0 + ty * 4 + i;
        if (m >= N) continue;
        for (int j = 0; j < 4; j++) {
            C[(size_t)m * M + col0 + tx * 4 + j] = acc[i][j];
        }
    }
}

// ---------------- edge aggregation + skip + bias + relu ----------------
// y[i] = relu( sum_{j->i} sigmoid(k[i]+q[j]) * v[j]  + s[i] + b )
// blockDim.x == D (128 or 512), one block per node
__global__ void edge_agg_kernel(const float* __restrict__ k, const float* __restrict__ q,
                                const float* __restrict__ v, const float* __restrict__ s,
                                const float* __restrict__ bias,
                                const int* __restrict__ offs, const int* __restrict__ csr_src,
                                float* __restrict__ y, int N, int D) {
    int i = blockIdx.x;
    int f = threadIdx.x;
    float kf = k[(size_t)i * D + f];
    float acc = 0.f;
    int e0 = offs[i], e1 = offs[i + 1];
    for (int e = e0; e < e1; e++) {
        int j = csr_src[e];
        float qf = q[(size_t)j * D + f];
        float vf = v[(size_t)j * D + f];
        float g = 1.f / (1.f + __expf(-(kf + qf)));
        acc += g * vf;
    }
    float val = acc + s[(size_t)i * D + f] + bias[f];
    y[(size_t)i * D + f] = val > 0.f ? val : 0.f;
}

// ---------------- batchnorm statistics (sum, sumsq per feature) ----------------
// grid: (D/64, ROWSPLIT); block 256 = 64 features x 4 rows
__global__ void col_stats_kernel(const float* __restrict__ y, int N, int D,
                                 float* __restrict__ sums, float* __restrict__ sumsq) {
    int f = blockIdx.x * 64 + (threadIdx.x & 63);
    int r0 = threadIdx.x >> 6;  // 0..3
    int rows_per = (N + gridDim.y - 1) / gridDim.y;
    int rs = blockIdx.y * rows_per;
    int re = min(rs + rows_per, N);
    float s = 0.f, s2 = 0.f;
    for (int r = rs + r0; r < re; r += 4) {
        float vv = y[(size_t)r * D + f];
        s += vv;
        s2 += vv * vv;
    }
    __shared__ float ls[2][256];
    ls[0][threadIdx.x] = s;
    ls[1][threadIdx.x] = s2;
    __syncthreads();
    if (threadIdx.x < 64) {
        float a = ls[0][threadIdx.x] + ls[0][threadIdx.x + 64] + ls[0][threadIdx.x + 128] + ls[0][threadIdx.x + 192];
        float b = ls[1][threadIdx.x] + ls[1][threadIdx.x + 64] + ls[1][threadIdx.x + 128] + ls[1][threadIdx.x + 192];
        atomicAdd(&sums[f], a);
        atomicAdd(&sumsq[f], b);
    }
}

// ---------------- batchnorm normalize (in place is safe: elementwise) ----------------
__global__ void bn_norm_kernel(const float* __restrict__ y, const float* __restrict__ sums,
                               const float* __restrict__ sumsq, const float* __restrict__ g,
                               const float* __restrict__ be, float* __restrict__ xout,
                               int N, int D) {
    int idx = blockIdx.x * blockDim.x + threadIdx.x;
    int total = N * D;
    float inv_n = 1.f / (float)N;
    if (idx < total) {
        int f = idx & (D - 1);  // D is power of two (128 or 512)
        float mu = sums[f] * inv_n;
        float var = sumsq[f] * inv_n - mu * mu;
        float inv = rsqrtf(var + EPS);
        xout[idx] = (y[idx] - mu) * inv * g[f] + be[f];
    }
}

// ---------------- global add pool ----------------
__global__ void pool_kernel(const float* __restrict__ x, const int* __restrict__ batch,
                            float* __restrict__ out, int N, int D) {
    int idx = blockIdx.x * blockDim.x + threadIdx.x;
    int total = N * D;
    if (idx < total) {
        int i = idx / D, f = idx - i * D;
        atomicAdd(&out[batch[i] * D + f], x[idx]);
    }
}

extern "C" void kernel_launch(void* const* d_in, const int* in_sizes, int n_in,
                              void* d_out, int out_size, void* d_ws, size_t ws_size,
                              hipStream_t stream) {
    const float* x_in = (const float*)d_in[0];
    const int* eidx = (const int*)d_in[1];
    const int* batch = (const int*)d_in[2];
    const int N = N_NODES;
    const int E = N_EDGES;
    const int* src = eidx;
    const int* dstp = eidx + E;

    const float *Wk[5], *Wq[5], *Wv[5], *Ws[5], *bb[5], *gg[5], *bebe[5];
    for (int l = 0; l < 5; l++) {
        Wk[l]  = (const float*)d_in[3 + l * 7 + 0];
        Wq[l]  = (const float*)d_in[3 + l * 7 + 1];
        Wv[l]  = (const float*)d_in[3 + l * 7 + 2];
        Ws[l]  = (const float*)d_in[3 + l * 7 + 3];
        bb[l]  = (const float*)d_in[3 + l * 7 + 4];
        gg[l]  = (const float*)d_in[3 + l * 7 + 5];
        bebe[l] = (const float*)d_in[3 + l * 7 + 6];
    }
    const int dims_in[5]  = {128, 512, 512, 128, 128};
    const int dims_out[5] = {512, 512, 128, 128, 128};

    // workspace carve
    char* w = (char*)d_ws;
    const size_t SZ = (size_t)N * 512 * sizeof(float);  // 20.48 MB
    float* kb = (float*)(w + 0 * SZ);
    float* qb = (float*)(w + 1 * SZ);
    float* vb = (float*)(w + 2 * SZ);
    float* sb = (float*)(w + 3 * SZ);
    float* yb = (float*)(w + 4 * SZ);
    float* bnsum = (float*)(w + 5 * SZ);        // 512 floats
    float* bnsq = bnsum + 512;                  // 512 floats
    int* counts = (int*)(w + 5 * SZ + 8192);
    int* offs = counts + 10016;                 // N+1 used
    int* pos = offs + 10016;
    int* csr = pos + 10016;                     // E ints

    hipMemsetAsync(counts, 0, (size_t)N * sizeof(int), stream);
    hipMemsetAsync(d_out, 0, (size_t)out_size * sizeof(float), stream);

    hist_kernel<<<(E + 255) / 256, 256, 0, stream>>>(dstp, counts, E);
    scan_kernel<<<1, 1024, 0, stream>>>(counts, offs, pos, N);
    scatter_kernel<<<(E + 255) / 256, 256, 0, stream>>>(src, dstp, pos, csr, E);

    const float* xcur = x_in;
    for (int l = 0; l < 5; l++) {
        int K = dims_in[l], M = dims_out[l];
        dim3 ggrid(M / BN, (N + BM - 1) / BM, 4);
        gemm4_kernel<<<ggrid, 256, 0, stream>>>(xcur, Wk[l], Wq[l], Wv[l], Ws[l],
                                                kb, qb, vb, sb, N, K, M);
        edge_agg_kernel<<<N, M, 0, stream>>>(kb, qb, vb, sb, bb[l], offs, csr, yb, N, M);
        hipMemsetAsync(bnsum, 0, 2 * 512 * sizeof(float), stream);
        dim3 gs(M / 64, 16);
        col_stats_kernel<<<gs, 256, 0, stream>>>(yb, N, M, bnsum, bnsq);
        int total = N * M;
        bn_norm_kernel<<<(total + 255) / 256, 256, 0, stream>>>(yb, bnsum, bnsq, gg[l], bebe[l],
                                                                yb, N, M);
        xcur = yb;  // normalized output is next layer's input (in-place over y)
    }
    pool_kernel<<<(N * 128 + 255) / 256, 256, 0, stream>>>(yb, batch, (float*)d_out, N, 128);
}

// Round 2
// 850.528 us; speedup vs baseline: 1.7384x; 1.7384x over previous
//
#include <hip/hip_runtime.h>
#include <hip/hip_bf16.h>

#define N_NODES 10000
#define N_PAD 10112   // 79 * 128
#define N_EDGES 160000
#define N_GRAPHS 64
#define EPS 1e-5f

typedef __attribute__((ext_vector_type(8))) short bf16x8;
typedef __attribute__((ext_vector_type(4))) float f32x4;

// ---------------- CSR build ----------------
__global__ void hist_kernel(const int* __restrict__ dst, int* __restrict__ counts, int E) {
    int e = blockIdx.x * blockDim.x + threadIdx.x;
    if (e < E) atomicAdd(&counts[dst[e]], 1);
}

__global__ void scan_kernel(const int* __restrict__ counts, int* __restrict__ offs,
                            int* __restrict__ pos, int n) {
    __shared__ int ls[1024];
    int t = threadIdx.x;
    int per = (n + 1023) / 1024;
    int st = t * per, en = min(st + per, n);
    int s = 0;
    for (int i = st; i < en; i++) s += counts[i];
    ls[t] = s;
    __syncthreads();
    for (int off = 1; off < 1024; off <<= 1) {
        int v = 0;
        if (t >= off) v = ls[t - off];
        __syncthreads();
        if (t >= off) ls[t] += v;
        __syncthreads();
    }
    int excl = (t == 0) ? 0 : ls[t - 1];
    for (int i = st; i < en; i++) {
        offs[i] = excl;
        pos[i] = excl;
        excl += counts[i];
    }
    if (t == 1023) offs[n] = ls[1023];
}

__global__ void scatter_kernel(const int* __restrict__ src, const int* __restrict__ dst,
                               int* __restrict__ pos, int* __restrict__ csr_src, int E) {
    int e = blockIdx.x * blockDim.x + threadIdx.x;
    if (e < E) {
        int p = atomicAdd(&pos[dst[e]], 1);
        csr_src[p] = src[e];
    }
}

// ---------------- cast x (f32 -> bf16) ----------------
__global__ void cast_x_kernel(const float* __restrict__ x, __hip_bfloat16* __restrict__ xb, int total) {
    int idx = blockIdx.x * blockDim.x + threadIdx.x;
    if (idx < total) xb[idx] = __float2bfloat16(x[idx]);
}

// ---------------- transpose + cast weights: Wt[m][k] = bf16(W[k][m]) ----------------
// grid (M/32, K/32, 4), block (32, 8)
__global__ void transpose_cast4_kernel(const float* __restrict__ W0, const float* __restrict__ W1,
                                       const float* __restrict__ W2, const float* __restrict__ W3,
                                       __hip_bfloat16* __restrict__ T0, __hip_bfloat16* __restrict__ T1,
                                       __hip_bfloat16* __restrict__ T2, __hip_bfloat16* __restrict__ T3,
                                       int K, int M) {
    const float* W;
    __hip_bfloat16* T;
    switch (blockIdx.z) {
        case 0: W = W0; T = T0; break;
        case 1: W = W1; T = T1; break;
        case 2: W = W2; T = T2; break;
        default: W = W3; T = T3; break;
    }
    __shared__ float tile[32][33];
    int m0 = blockIdx.x * 32, k0 = blockIdx.y * 32;
#pragma unroll
    for (int i = 0; i < 4; i++) {
        int kk = k0 + threadIdx.y + i * 8;
        tile[threadIdx.y + i * 8][threadIdx.x] = W[(size_t)kk * M + m0 + threadIdx.x];
    }
    __syncthreads();
#pragma unroll
    for (int i = 0; i < 4; i++) {
        int mm = m0 + threadIdx.y + i * 8;
        T[(size_t)mm * K + k0 + threadIdx.x] = __float2bfloat16(tile[threadIdx.x][threadIdx.y + i * 8]);
    }
}

// ---------------- fused 4-matrix bf16 MFMA GEMM ----------------
// C = X @ W ; X: [N_PAD, K] bf16 row-major, Wt: [M, K] bf16 row-major (W transposed)
// C: [N, M] f32 row-major. blockIdx.z selects (Wt, C).
// Tile 128x128, BK=32, 256 threads = 4 waves (2x2 of 64x64).
// LDS layout (A and B identical): elem(row, kchunk, j) at  kchunk*1024 + row*8 + j
// so frag ds_read_b128 is lane-contiguous (conflict-free).
__global__ __launch_bounds__(256) void gemm4_mfma_kernel(
    const __hip_bfloat16* __restrict__ X,
    const __hip_bfloat16* __restrict__ T0, const __hip_bfloat16* __restrict__ T1,
    const __hip_bfloat16* __restrict__ T2, const __hip_bfloat16* __restrict__ T3,
    float* __restrict__ C0, float* __restrict__ C1,
    float* __restrict__ C2, float* __restrict__ C3,
    int N, int K, int M) {
    const __hip_bfloat16* Bt;
    float* C;
    switch (blockIdx.z) {
        case 0: Bt = T0; C = C0; break;
        case 1: Bt = T1; C = C1; break;
        case 2: Bt = T2; C = C2; break;
        default: Bt = T3; C = C3; break;
    }
    __shared__ __align__(16) short As[4096];  // 4 kchunks * 128 rows * 8
    __shared__ __align__(16) short Bs[4096];

    int tid = threadIdx.x;
    int wave = tid >> 6, lane = tid & 63;
    int wrow = wave >> 1, wcol = wave & 1;
    int l15 = lane & 15, lk = lane >> 4;
    int row0 = blockIdx.y * 128, col0 = blockIdx.x * 128;

    f32x4 acc[4][4] = {};

    const short* Xs = (const short*)X;
    const short* Bts = (const short*)Bt;

    for (int kt = 0; kt < K; kt += 32) {
#pragma unroll
        for (int i = 0; i < 2; i++) {
            int idx = i * 256 + tid;
            int kc = idx >> 7, r = idx & 127;
            const short* gA = Xs + (size_t)(row0 + r) * K + kt + kc * 8;
            short* lA = As + (size_t)(i * 256 + wave * 64) * 8;
            __builtin_amdgcn_global_load_lds(
                (const __attribute__((address_space(1))) unsigned int*)gA,
                (__attribute__((address_space(3))) unsigned int*)lA, 16, 0, 0);
            const short* gB = Bts + (size_t)(col0 + r) * K + kt + kc * 8;
            short* lB = Bs + (size_t)(i * 256 + wave * 64) * 8;
            __builtin_amdgcn_global_load_lds(
                (const __attribute__((address_space(1))) unsigned int*)gB,
                (__attribute__((address_space(3))) unsigned int*)lB, 16, 0, 0);
        }
        __syncthreads();

        bf16x8 a[4], b[4];
#pragma unroll
        for (int i = 0; i < 4; i++)
            a[i] = *(const bf16x8*)&As[lk * 1024 + (wrow * 64 + i * 16 + l15) * 8];
#pragma unroll
        for (int j = 0; j < 4; j++)
            b[j] = *(const bf16x8*)&Bs[lk * 1024 + (wcol * 64 + j * 16 + l15) * 8];
#pragma unroll
        for (int i = 0; i < 4; i++)
#pragma unroll
            for (int j = 0; j < 4; j++)
                acc[i][j] = __builtin_amdgcn_mfma_f32_16x16x32_bf16(a[i], b[j], acc[i][j], 0, 0, 0);
        __syncthreads();
    }

#pragma unroll
    for (int i = 0; i < 4; i++) {
#pragma unroll
        for (int r = 0; r < 4; r++) {
            int row = row0 + wrow * 64 + i * 16 + lk * 4 + r;
            if (row < N) {
#pragma unroll
                for (int j = 0; j < 4; j++) {
                    C[(size_t)row * M + col0 + wcol * 64 + j * 16 + l15] = acc[i][j][r];
                }
            }
        }
    }
}

// ---------------- edge aggregation + skip + bias + relu (wave per node, float2) ----------------
template <int NV2>
__global__ __launch_bounds__(64) void edge_agg_kernel(
    const float* __restrict__ k, const float* __restrict__ q,
    const float* __restrict__ v, const float* __restrict__ s,
    const float* __restrict__ bias,
    const int* __restrict__ offs, const int* __restrict__ csr_src,
    float* __restrict__ y, int D) {
    int i = blockIdx.x;
    int t = threadIdx.x;
    size_t base = (size_t)i * D;
    float2 kf[NV2], acc[NV2];
#pragma unroll
    for (int w = 0; w < NV2; w++) {
        kf[w] = ((const float2*)(k + base))[t + 64 * w];
        acc[w].x = 0.f;
        acc[w].y = 0.f;
    }
    int e0 = offs[i], e1 = offs[i + 1];
    for (int e = e0; e < e1; e++) {
        int j = csr_src[e];
        size_t jb = (size_t)j * D;
#pragma unroll
        for (int w = 0; w < NV2; w++) {
            float2 qq = ((const float2*)(q + jb))[t + 64 * w];
            float2 vv = ((const float2*)(v + jb))[t + 64 * w];
            float gx = 1.f / (1.f + __expf(-(kf[w].x + qq.x)));
            float gy = 1.f / (1.f + __expf(-(kf[w].y + qq.y)));
            acc[w].x += gx * vv.x;
            acc[w].y += gy * vv.y;
        }
    }
#pragma unroll
    for (int w = 0; w < NV2; w++) {
        float2 ss = ((const float2*)(s + base))[t + 64 * w];
        float2 bv = ((const float2*)bias)[t + 64 * w];
        float ox = acc[w].x + ss.x + bv.x;
        float oy = acc[w].y + ss.y + bv.y;
        float2 o;
        o.x = ox > 0.f ? ox : 0.f;
        o.y = oy > 0.f ? oy : 0.f;
        ((float2*)(y + base))[t + 64 * w] = o;
    }
}

// ---------------- batchnorm statistics ----------------
__global__ void col_stats_kernel(const float* __restrict__ y, int N, int D,
                                 float* __restrict__ sums, float* __restrict__ sumsq) {
    int f = blockIdx.x * 64 + (threadIdx.x & 63);
    int r0 = threadIdx.x >> 6;
    int rows_per = (N + gridDim.y - 1) / gridDim.y;
    int rs = blockIdx.y * rows_per;
    int re = min(rs + rows_per, N);
    float s = 0.f, s2 = 0.f;
    for (int r = rs + r0; r < re; r += 4) {
        float vv = y[(size_t)r * D + f];
        s += vv;
        s2 += vv * vv;
    }
    __shared__ float ls[2][256];
    ls[0][threadIdx.x] = s;
    ls[1][threadIdx.x] = s2;
    __syncthreads();
    if (threadIdx.x < 64) {
        float a = ls[0][threadIdx.x] + ls[0][threadIdx.x + 64] + ls[0][threadIdx.x + 128] + ls[0][threadIdx.x + 192];
        float b = ls[1][threadIdx.x] + ls[1][threadIdx.x + 64] + ls[1][threadIdx.x + 128] + ls[1][threadIdx.x + 192];
        atomicAdd(&sums[f], a);
        atomicAdd(&sumsq[f], b);
    }
}

// ---------------- batchnorm normalize + cast to bf16 for next layer ----------------
template <bool WF32>
__global__ void bn_norm_kernel(const float* __restrict__ y, const float* __restrict__ sums,
                               const float* __restrict__ sumsq, const float* __restrict__ g,
                               const float* __restrict__ be, __hip_bfloat16* __restrict__ xb,
                               float* __restrict__ yout, int N, int D) {
    int idx = blockIdx.x * blockDim.x + threadIdx.x;
    int total = N * D;
    float inv_n = 1.f / (float)N;
    if (idx < total) {
        int f = idx & (D - 1);
        float mu = sums[f] * inv_n;
        float var = sumsq[f] * inv_n - mu * mu;
        float inv = rsqrtf(var + EPS);
        float val = (y[idx] - mu) * inv * g[f] + be[f];
        xb[idx] = __float2bfloat16(val);
        if (WF32) yout[idx] = val;
    }
}

// ---------------- global add pool ----------------
__global__ void pool_kernel(const float* __restrict__ x, const int* __restrict__ batch,
                            float* __restrict__ out, int N, int D) {
    int idx = blockIdx.x * blockDim.x + threadIdx.x;
    int total = N * D;
    if (idx < total) {
        int i = idx / D, f = idx - i * D;
        atomicAdd(&out[batch[i] * D + f], x[idx]);
    }
}

extern "C" void kernel_launch(void* const* d_in, const int* in_sizes, int n_in,
                              void* d_out, int out_size, void* d_ws, size_t ws_size,
                              hipStream_t stream) {
    const float* x_in = (const float*)d_in[0];
    const int* eidx = (const int*)d_in[1];
    const int* batch = (const int*)d_in[2];
    const int N = N_NODES;
    const int E = N_EDGES;
    const int* src = eidx;
    const int* dstp = eidx + E;

    const float *Wk[5], *Wq[5], *Wv[5], *Ws[5], *bb[5], *gg[5], *bebe[5];
    for (int l = 0; l < 5; l++) {
        Wk[l]   = (const float*)d_in[3 + l * 7 + 0];
        Wq[l]   = (const float*)d_in[3 + l * 7 + 1];
        Wv[l]   = (const float*)d_in[3 + l * 7 + 2];
        Ws[l]   = (const float*)d_in[3 + l * 7 + 3];
        bb[l]   = (const float*)d_in[3 + l * 7 + 4];
        gg[l]   = (const float*)d_in[3 + l * 7 + 5];
        bebe[l] = (const float*)d_in[3 + l * 7 + 6];
    }
    const int dims_in[5]  = {128, 512, 512, 128, 128};
    const int dims_out[5] = {512, 512, 128, 128, 128};

    // ---- workspace carve ----
    char* w = (char*)d_ws;
    const size_t SZ = (size_t)N * 512 * sizeof(float);  // 20.48 MB
    float* kb = (float*)(w + 0 * SZ);
    float* qb = (float*)(w + 1 * SZ);
    float* vb = (float*)(w + 2 * SZ);
    float* sb = (float*)(w + 3 * SZ);
    float* yb = (float*)(w + 4 * SZ);
    char* p = w + 5 * SZ;
    __hip_bfloat16* xb = (__hip_bfloat16*)p;            // N_PAD x 512 bf16
    p += (size_t)N_PAD * 512 * sizeof(__hip_bfloat16);
    float* bnsum = (float*)p;
    float* bnsq = bnsum + 512;
    p += 4096;
    int* counts = (int*)p;
    int* offs = counts + 10016;
    int* pos = offs + 10016;
    int* csr = pos + 10016;
    p += (3 * 10016 + N_EDGES) * sizeof(int);
    p = (char*)(((uintptr_t)p + 255) & ~(uintptr_t)255);
    // transposed bf16 weights, 4 per layer
    __hip_bfloat16* Wt[5][4];
    const int wsz[5] = {128 * 512, 512 * 512, 512 * 128, 128 * 128, 128 * 128};
    for (int l = 0; l < 5; l++) {
        for (int m = 0; m < 4; m++) {
            Wt[l][m] = (__hip_bfloat16*)p;
            p += (size_t)wsz[l] * sizeof(__hip_bfloat16);
        }
    }

    hipMemsetAsync(counts, 0, (size_t)N * sizeof(int), stream);
    hipMemsetAsync(d_out, 0, (size_t)out_size * sizeof(float), stream);

    hist_kernel<<<(E + 255) / 256, 256, 0, stream>>>(dstp, counts, E);
    scan_kernel<<<1, 1024, 0, stream>>>(counts, offs, pos, N);
    scatter_kernel<<<(E + 255) / 256, 256, 0, stream>>>(src, dstp, pos, csr, E);

    cast_x_kernel<<<(N * 128 + 255) / 256, 256, 0, stream>>>(x_in, xb, N * 128);
    for (int l = 0; l < 5; l++) {
        int K = dims_in[l], M = dims_out[l];
        dim3 tg(M / 32, K / 32, 4);
        transpose_cast4_kernel<<<tg, dim3(32, 8), 0, stream>>>(
            Wk[l], Wq[l], Wv[l], Ws[l], Wt[l][0], Wt[l][1], Wt[l][2], Wt[l][3], K, M);
    }

    for (int l = 0; l < 5; l++) {
        int K = dims_in[l], M = dims_out[l];
        dim3 ggrid(M / 128, N_PAD / 128, 4);
        gemm4_mfma_kernel<<<ggrid, 256, 0, stream>>>(xb, Wt[l][0], Wt[l][1], Wt[l][2], Wt[l][3],
                                                     kb, qb, vb, sb, N, K, M);
        if (M == 512)
            edge_agg_kernel<4><<<N, 64, 0, stream>>>(kb, qb, vb, sb, bb[l], offs, csr, yb, M);
        else
            edge_agg_kernel<1><<<N, 64, 0, stream>>>(kb, qb, vb, sb, bb[l], offs, csr, yb, M);
        hipMemsetAsync(bnsum, 0, 2 * 512 * sizeof(float), stream);
        dim3 gs(M / 64, 16);
        col_stats_kernel<<<gs, 256, 0, stream>>>(yb, N, M, bnsum, bnsq);
        int total = N * M;
        if (l == 4)
            bn_norm_kernel<true><<<(total + 255) / 256, 256, 0, stream>>>(yb, bnsum, bnsq, gg[l], bebe[l], xb, yb, N, M);
        else
            bn_norm_kernel<false><<<(total + 255) / 256, 256, 0, stream>>>(yb, bnsum, bnsq, gg[l], bebe[l], xb, yb, N, M);
    }
    pool_kernel<<<(N * 128 + 255) / 256, 256, 0, stream>>>(yb, batch, (float*)d_out, N, 128);
}

// Round 3
// 713.129 us; speedup vs baseline: 2.0734x; 1.1927x over previous
//
#include <hip/hip_runtime.h>
#include <hip/hip_bf16.h>

#define N_NODES 10000
#define N_PAD 10112   // 79 * 128
#define N_EDGES 160000
#define N_GRAPHS 64
#define EPS 1e-5f

typedef __attribute__((ext_vector_type(8))) short bf16x8;
typedef __attribute__((ext_vector_type(4))) float f32x4;

__device__ inline float b2f(unsigned short u) {
    return __uint_as_float(((unsigned)u) << 16);
}
__device__ inline float sigmoid_fast(float x) {
    return __builtin_amdgcn_rcpf(1.f + __expf(-x));
}

// ---------------- CSR build ----------------
__global__ void hist_kernel(const int* __restrict__ dst, int* __restrict__ counts, int E) {
    int e = blockIdx.x * blockDim.x + threadIdx.x;
    if (e < E) atomicAdd(&counts[dst[e]], 1);
}

__global__ void scan_kernel(const int* __restrict__ counts, int* __restrict__ offs,
                            int* __restrict__ pos, int n) {
    __shared__ int ls[1024];
    int t = threadIdx.x;
    int per = (n + 1023) / 1024;
    int st = t * per, en = min(st + per, n);
    int s = 0;
    for (int i = st; i < en; i++) s += counts[i];
    ls[t] = s;
    __syncthreads();
    for (int off = 1; off < 1024; off <<= 1) {
        int v = 0;
        if (t >= off) v = ls[t - off];
        __syncthreads();
        if (t >= off) ls[t] += v;
        __syncthreads();
    }
    int excl = (t == 0) ? 0 : ls[t - 1];
    for (int i = st; i < en; i++) {
        offs[i] = excl;
        pos[i] = excl;
        excl += counts[i];
    }
    if (t == 1023) offs[n] = ls[1023];
}

__global__ void scatter_kernel(const int* __restrict__ src, const int* __restrict__ dst,
                               int* __restrict__ pos, int* __restrict__ csr_src, int E) {
    int e = blockIdx.x * blockDim.x + threadIdx.x;
    if (e < E) {
        int p = atomicAdd(&pos[dst[e]], 1);
        csr_src[p] = src[e];
    }
}

// ---------------- cast x (f32 -> bf16) ----------------
__global__ void cast_x_kernel(const float* __restrict__ x, __hip_bfloat16* __restrict__ xb, int total) {
    int idx = blockIdx.x * blockDim.x + threadIdx.x;
    if (idx < total) xb[idx] = __float2bfloat16(x[idx]);
}

// ---------------- transpose + cast weights: Wt[m][k] = bf16(W[k][m]) ----------------
__global__ void transpose_cast4_kernel(const float* __restrict__ W0, const float* __restrict__ W1,
                                       const float* __restrict__ W2, const float* __restrict__ W3,
                                       __hip_bfloat16* __restrict__ T0, __hip_bfloat16* __restrict__ T1,
                                       __hip_bfloat16* __restrict__ T2, __hip_bfloat16* __restrict__ T3,
                                       int K, int M) {
    const float* W;
    __hip_bfloat16* T;
    switch (blockIdx.z) {
        case 0: W = W0; T = T0; break;
        case 1: W = W1; T = T1; break;
        case 2: W = W2; T = T2; break;
        default: W = W3; T = T3; break;
    }
    __shared__ float tile[32][33];
    int m0 = blockIdx.x * 32, k0 = blockIdx.y * 32;
#pragma unroll
    for (int i = 0; i < 4; i++) {
        int kk = k0 + threadIdx.y + i * 8;
        tile[threadIdx.y + i * 8][threadIdx.x] = W[(size_t)kk * M + m0 + threadIdx.x];
    }
    __syncthreads();
#pragma unroll
    for (int i = 0; i < 4; i++) {
        int mm = m0 + threadIdx.y + i * 8;
        T[(size_t)mm * K + k0 + threadIdx.x] = __float2bfloat16(tile[threadIdx.x][threadIdx.y + i * 8]);
    }
}

// ---------------- fused 4-matrix bf16 MFMA GEMM ----------------
// z=0 -> k (f32), z=1 -> q (bf16), z=2 -> v (bf16), z=3 -> s (f32)
__global__ __launch_bounds__(256) void gemm4_mfma_kernel(
    const __hip_bfloat16* __restrict__ X,
    const __hip_bfloat16* __restrict__ T0, const __hip_bfloat16* __restrict__ T1,
    const __hip_bfloat16* __restrict__ T2, const __hip_bfloat16* __restrict__ T3,
    float* __restrict__ Ck, unsigned short* __restrict__ Q16,
    unsigned short* __restrict__ V16, float* __restrict__ Cs,
    int N, int K, int M) {
    const __hip_bfloat16* Bt;
    switch (blockIdx.z) {
        case 0: Bt = T0; break;
        case 1: Bt = T1; break;
        case 2: Bt = T2; break;
        default: Bt = T3; break;
    }
    __shared__ __align__(16) short As[4096];  // 4 kchunks * 128 rows * 8
    __shared__ __align__(16) short Bs[4096];

    int tid = threadIdx.x;
    int wave = tid >> 6, lane = tid & 63;
    int wrow = wave >> 1, wcol = wave & 1;
    int l15 = lane & 15, lk = lane >> 4;
    int row0 = blockIdx.y * 128, col0 = blockIdx.x * 128;

    f32x4 acc[4][4] = {};

    const short* Xs = (const short*)X;
    const short* Bts = (const short*)Bt;

    for (int kt = 0; kt < K; kt += 32) {
#pragma unroll
        for (int i = 0; i < 2; i++) {
            int idx = i * 256 + tid;
            int kc = idx >> 7, r = idx & 127;
            const short* gA = Xs + (size_t)(row0 + r) * K + kt + kc * 8;
            short* lA = As + (size_t)(i * 256 + wave * 64) * 8;
            __builtin_amdgcn_global_load_lds(
                (const __attribute__((address_space(1))) unsigned int*)gA,
                (__attribute__((address_space(3))) unsigned int*)lA, 16, 0, 0);
            const short* gB = Bts + (size_t)(col0 + r) * K + kt + kc * 8;
            short* lB = Bs + (size_t)(i * 256 + wave * 64) * 8;
            __builtin_amdgcn_global_load_lds(
                (const __attribute__((address_space(1))) unsigned int*)gB,
                (__attribute__((address_space(3))) unsigned int*)lB, 16, 0, 0);
        }
        __syncthreads();

        bf16x8 a[4], b[4];
#pragma unroll
        for (int i = 0; i < 4; i++)
            a[i] = *(const bf16x8*)&As[lk * 1024 + (wrow * 64 + i * 16 + l15) * 8];
#pragma unroll
        for (int j = 0; j < 4; j++)
            b[j] = *(const bf16x8*)&Bs[lk * 1024 + (wcol * 64 + j * 16 + l15) * 8];
#pragma unroll
        for (int i = 0; i < 4; i++)
#pragma unroll
            for (int j = 0; j < 4; j++)
                acc[i][j] = __builtin_amdgcn_mfma_f32_16x16x32_bf16(a[i], b[j], acc[i][j], 0, 0, 0);
        __syncthreads();
    }

    bool isbf = (blockIdx.z == 1) || (blockIdx.z == 2);
    if (isbf) {
        unsigned short* Cb = (blockIdx.z == 1) ? Q16 : V16;
#pragma unroll
        for (int i = 0; i < 4; i++) {
#pragma unroll
            for (int r = 0; r < 4; r++) {
                int row = row0 + wrow * 64 + i * 16 + lk * 4 + r;
                if (row < N) {
#pragma unroll
                    for (int j = 0; j < 4; j++) {
                        __hip_bfloat16 hv = __float2bfloat16(acc[i][j][r]);
                        Cb[(size_t)row * M + col0 + wcol * 64 + j * 16 + l15] =
                            *(unsigned short*)&hv;
                    }
                }
            }
        }
    } else {
        float* Cf = (blockIdx.z == 0) ? Ck : Cs;
#pragma unroll
        for (int i = 0; i < 4; i++) {
#pragma unroll
            for (int r = 0; r < 4; r++) {
                int row = row0 + wrow * 64 + i * 16 + lk * 4 + r;
                if (row < N) {
#pragma unroll
                    for (int j = 0; j < 4; j++) {
                        Cf[(size_t)row * M + col0 + wcol * 64 + j * 16 + l15] = acc[i][j][r];
                    }
                }
            }
        }
    }
}

// ---------------- edge aggregation (bf16 gathers) + skip + bias + relu ----------------
// D=512: one wave per node, lane holds 8 consecutive feats (one bf16x8 load per row)
__global__ __launch_bounds__(64) void edge_agg512_kernel(
    const float* __restrict__ k, const unsigned short* __restrict__ q,
    const unsigned short* __restrict__ v, const float* __restrict__ s,
    const float* __restrict__ bias,
    const int* __restrict__ offs, const int* __restrict__ csr_src,
    float* __restrict__ y) {
    const int D = 512;
    int i = blockIdx.x, t = threadIdx.x;
    size_t base = (size_t)i * D;
    int f0 = t * 8;
    float kf[8], acc[8] = {};
    float4 k0 = *(const float4*)(k + base + f0);
    float4 k1 = *(const float4*)(k + base + f0 + 4);
    kf[0] = k0.x; kf[1] = k0.y; kf[2] = k0.z; kf[3] = k0.w;
    kf[4] = k1.x; kf[5] = k1.y; kf[6] = k1.z; kf[7] = k1.w;
    int e0 = offs[i], e1 = offs[i + 1];
    for (int e = e0; e < e1; e++) {
        int j = csr_src[e];
        size_t jb = (size_t)j * D + f0;
        bf16x8 qq = *(const bf16x8*)(q + jb);
        bf16x8 vv = *(const bf16x8*)(v + jb);
#pragma unroll
        for (int w = 0; w < 8; w++) {
            float qf = b2f((unsigned short)qq[w]);
            float vf = b2f((unsigned short)vv[w]);
            acc[w] += sigmoid_fast(kf[w] + qf) * vf;
        }
    }
#pragma unroll
    for (int w = 0; w < 8; w += 4) {
        float4 ss = *(const float4*)(s + base + f0 + w);
        float4 bv = *(const float4*)(bias + f0 + w);
        float4 o;
        o.x = acc[w + 0] + ss.x + bv.x;
        o.y = acc[w + 1] + ss.y + bv.y;
        o.z = acc[w + 2] + ss.z + bv.z;
        o.w = acc[w + 3] + ss.w + bv.w;
        o.x = o.x > 0.f ? o.x : 0.f;
        o.y = o.y > 0.f ? o.y : 0.f;
        o.z = o.z > 0.f ? o.z : 0.f;
        o.w = o.w > 0.f ? o.w : 0.f;
        *(float4*)(y + base + f0 + w) = o;
    }
}

// D=128: one wave per node, lane holds 2 feats (uint load per row)
__global__ __launch_bounds__(64) void edge_agg128_kernel(
    const float* __restrict__ k, const unsigned short* __restrict__ q,
    const unsigned short* __restrict__ v, const float* __restrict__ s,
    const float* __restrict__ bias,
    const int* __restrict__ offs, const int* __restrict__ csr_src,
    float* __restrict__ y) {
    const int D = 128;
    int i = blockIdx.x, t = threadIdx.x;
    size_t base = (size_t)i * D;
    int f0 = t * 2;
    float2 kf = *(const float2*)(k + base + f0);
    float accx = 0.f, accy = 0.f;
    int e0 = offs[i], e1 = offs[i + 1];
    for (int e = e0; e < e1; e++) {
        int j = csr_src[e];
        size_t jb = (size_t)j * D + f0;
        unsigned qq = *(const unsigned*)(q + jb);
        unsigned vv = *(const unsigned*)(v + jb);
        float q0 = __uint_as_float(qq << 16);
        float q1 = __uint_as_float(qq & 0xFFFF0000u);
        float v0 = __uint_as_float(vv << 16);
        float v1 = __uint_as_float(vv & 0xFFFF0000u);
        accx += sigmoid_fast(kf.x + q0) * v0;
        accy += sigmoid_fast(kf.y + q1) * v1;
    }
    float2 ss = *(const float2*)(s + base + f0);
    float2 bv = *(const float2*)(bias + f0);
    float ox = accx + ss.x + bv.x;
    float oy = accy + ss.y + bv.y;
    float2 o;
    o.x = ox > 0.f ? ox : 0.f;
    o.y = oy > 0.f ? oy : 0.f;
    *(float2*)(y + base + f0) = o;
}

// ---------------- batchnorm statistics ----------------
__global__ void col_stats_kernel(const float* __restrict__ y, int N, int D,
                                 float* __restrict__ sums, float* __restrict__ sumsq) {
    int f = blockIdx.x * 64 + (threadIdx.x & 63);
    int r0 = threadIdx.x >> 6;
    int rows_per = (N + gridDim.y - 1) / gridDim.y;
    int rs = blockIdx.y * rows_per;
    int re = min(rs + rows_per, N);
    float s = 0.f, s2 = 0.f;
    for (int r = rs + r0; r < re; r += 4) {
        float vv = y[(size_t)r * D + f];
        s += vv;
        s2 += vv * vv;
    }
    __shared__ float ls[2][256];
    ls[0][threadIdx.x] = s;
    ls[1][threadIdx.x] = s2;
    __syncthreads();
    if (threadIdx.x < 64) {
        float a = ls[0][threadIdx.x] + ls[0][threadIdx.x + 64] + ls[0][threadIdx.x + 128] + ls[0][threadIdx.x + 192];
        float b = ls[1][threadIdx.x] + ls[1][threadIdx.x + 64] + ls[1][threadIdx.x + 128] + ls[1][threadIdx.x + 192];
        atomicAdd(&sums[f], a);
        atomicAdd(&sumsq[f], b);
    }
}

// ---------------- batchnorm normalize + cast to bf16 for next layer ----------------
__global__ void bn_norm_kernel(const float* __restrict__ y, const float* __restrict__ sums,
                               const float* __restrict__ sumsq, const float* __restrict__ g,
                               const float* __restrict__ be, __hip_bfloat16* __restrict__ xb,
                               int N, int D) {
    int idx = blockIdx.x * blockDim.x + threadIdx.x;
    int total = N * D;
    float inv_n = 1.f / (float)N;
    if (idx < total) {
        int f = idx & (D - 1);
        float mu = sums[f] * inv_n;
        float var = sumsq[f] * inv_n - mu * mu;
        float inv = rsqrtf(var + EPS);
        float val = (y[idx] - mu) * inv * g[f] + be[f];
        xb[idx] = __float2bfloat16(val);
    }
}

// ---------------- last-layer batchnorm normalize fused with global add pool ----------------
__global__ void bn_norm_pool_kernel(const float* __restrict__ y, const float* __restrict__ sums,
                                    const float* __restrict__ sumsq, const float* __restrict__ g,
                                    const float* __restrict__ be, const int* __restrict__ batch,
                                    float* __restrict__ out, int N, int D) {
    int idx = blockIdx.x * blockDim.x + threadIdx.x;
    int total = N * D;
    float inv_n = 1.f / (float)N;
    if (idx < total) {
        int f = idx & (D - 1);
        int i = idx >> 7;  // D == 128
        float mu = sums[f] * inv_n;
        float var = sumsq[f] * inv_n - mu * mu;
        float inv = rsqrtf(var + EPS);
        float val = (y[idx] - mu) * inv * g[f] + be[f];
        atomicAdd(&out[batch[i] * D + f], val);
    }
}

extern "C" void kernel_launch(void* const* d_in, const int* in_sizes, int n_in,
                              void* d_out, int out_size, void* d_ws, size_t ws_size,
                              hipStream_t stream) {
    const float* x_in = (const float*)d_in[0];
    const int* eidx = (const int*)d_in[1];
    const int* batch = (const int*)d_in[2];
    const int N = N_NODES;
    const int E = N_EDGES;
    const int* src = eidx;
    const int* dstp = eidx + E;

    const float *Wk[5], *Wq[5], *Wv[5], *Ws[5], *bb[5], *gg[5], *bebe[5];
    for (int l = 0; l < 5; l++) {
        Wk[l]   = (const float*)d_in[3 + l * 7 + 0];
        Wq[l]   = (const float*)d_in[3 + l * 7 + 1];
        Wv[l]   = (const float*)d_in[3 + l * 7 + 2];
        Ws[l]   = (const float*)d_in[3 + l * 7 + 3];
        bb[l]   = (const float*)d_in[3 + l * 7 + 4];
        gg[l]   = (const float*)d_in[3 + l * 7 + 5];
        bebe[l] = (const float*)d_in[3 + l * 7 + 6];
    }
    const int dims_in[5]  = {128, 512, 512, 128, 128};
    const int dims_out[5] = {512, 512, 128, 128, 128};

    // ---- workspace carve ----
    char* w = (char*)d_ws;
    const size_t SZF = (size_t)N * 512 * sizeof(float);       // 20.48 MB
    const size_t SZH = (size_t)N * 512 * sizeof(short);       // 10.24 MB
    float* kb = (float*)w;                     w += SZF;
    unsigned short* qb16 = (unsigned short*)w; w += SZH;
    unsigned short* vb16 = (unsigned short*)w; w += SZH;
    float* sb = (float*)w;                     w += SZF;
    float* yb = (float*)w;                     w += SZF;
    __hip_bfloat16* xb = (__hip_bfloat16*)w;   w += (size_t)N_PAD * 512 * sizeof(short);
    float* bnbuf = (float*)w;                  w += 5 * 1024 * sizeof(float);  // 5 layers x (512 sum + 512 sq)
    int* counts = (int*)w;
    int* offs = counts + 10016;
    int* pos = offs + 10016;
    int* csr = pos + 10016;
    w += (3 * 10016 + N_EDGES) * sizeof(int);
    w = (char*)(((uintptr_t)w + 255) & ~(uintptr_t)255);
    __hip_bfloat16* Wt[5][4];
    const int wsz[5] = {128 * 512, 512 * 512, 512 * 128, 128 * 128, 128 * 128};
    for (int l = 0; l < 5; l++) {
        for (int m = 0; m < 4; m++) {
            Wt[l][m] = (__hip_bfloat16*)w;
            w += (size_t)wsz[l] * sizeof(short);
        }
    }

    hipMemsetAsync(counts, 0, (size_t)N * sizeof(int), stream);
    hipMemsetAsync(bnbuf, 0, 5 * 1024 * sizeof(float), stream);
    hipMemsetAsync(d_out, 0, (size_t)out_size * sizeof(float), stream);

    hist_kernel<<<(E + 255) / 256, 256, 0, stream>>>(dstp, counts, E);
    scan_kernel<<<1, 1024, 0, stream>>>(counts, offs, pos, N);
    scatter_kernel<<<(E + 255) / 256, 256, 0, stream>>>(src, dstp, pos, csr, E);

    cast_x_kernel<<<(N * 128 + 255) / 256, 256, 0, stream>>>(x_in, xb, N * 128);
    for (int l = 0; l < 5; l++) {
        int K = dims_in[l], M = dims_out[l];
        dim3 tg(M / 32, K / 32, 4);
        transpose_cast4_kernel<<<tg, dim3(32, 8), 0, stream>>>(
            Wk[l], Wq[l], Wv[l], Ws[l], Wt[l][0], Wt[l][1], Wt[l][2], Wt[l][3], K, M);
    }

    for (int l = 0; l < 5; l++) {
        int K = dims_in[l], M = dims_out[l];
        float* bnsum = bnbuf + l * 1024;
        float* bnsq = bnsum + 512;
        dim3 ggrid(M / 128, N_PAD / 128, 4);
        gemm4_mfma_kernel<<<ggrid, 256, 0, stream>>>(xb, Wt[l][0], Wt[l][1], Wt[l][2], Wt[l][3],
                                                     kb, qb16, vb16, sb, N, K, M);
        if (M == 512)
            edge_agg512_kernel<<<N, 64, 0, stream>>>(kb, qb16, vb16, sb, bb[l], offs, csr, yb);
        else
            edge_agg128_kernel<<<N, 64, 0, stream>>>(kb, qb16, vb16, sb, bb[l], offs, csr, yb);
        dim3 gs(M / 64, 16);
        col_stats_kernel<<<gs, 256, 0, stream>>>(yb, N, M, bnsum, bnsq);
        int total = N * M;
        if (l == 4)
            bn_norm_pool_kernel<<<(total + 255) / 256, 256, 0, stream>>>(
                yb, bnsum, bnsq, gg[l], bebe[l], batch, (float*)d_out, N, M);
        else
            bn_norm_kernel<<<(total + 255) / 256, 256, 0, stream>>>(
                yb, bnsum, bnsq, gg[l], bebe[l], xb, N, M);
    }
}